// Round 15
// baseline (1165.877 us; speedup 1.0000x reference)
//
#include <hip/hip_runtime.h>
#include <hip/hip_fp16.h>

// MoE: B=4 S=2048 D=1024 E=8 K=2 H=4096. T=8192 tokens, 16384 assignments.
// R15 (isolated): fragment LDS reads -> inline-asm ds_read_b128, invisible
// to LLVM's waitcnt pass. Theory: the pass treats global_load_lds as an LDS
// write aliasing the later ds_reads of the same smem object and inserts
// vmcnt(0) before them -> counted VMCNT(4/6) dead, pipeline depth 0 ->
// explains ALL seven schedule-null rounds (13.6k cyc/iter = 2x template).
// Manual hazard per rule #18: lgkmcnt(0) + sched_barrier(0) after each
// opening barrier (m201 phase form). All else = R14.

#define T_TOK 8192
#define D_IN  1024
#define E_EXP 8
#define H_HID 4096
#define NSLOT (T_TOK * 2)
#define NSLOT_PAD (NSLOT + 256)
#define KSPLIT 4

typedef _Float16 f16;
typedef __attribute__((ext_vector_type(8))) _Float16 f16x8;
typedef __attribute__((ext_vector_type(4))) _Float16 f16x4;
typedef __attribute__((ext_vector_type(4))) float f32x4;

__device__ __forceinline__ void gload_lds16(const void* g, void* l) {
  __builtin_amdgcn_global_load_lds(
      (const __attribute__((address_space(1))) unsigned int*)g,
      (__attribute__((address_space(3))) unsigned int*)l, 16, 0, 0);
}

// inline-asm LDS read: flat->LDS address is the low 32 bits (shared aperture
// is 4GB-aligned); untracked by SIInsertWaitcnts -> no auto vmcnt/lgkm waits.
__device__ __forceinline__ f16x8 dsrd(const void* p) {
  f16x8 r;
  unsigned a = (unsigned)(unsigned long long)p;
  asm volatile("ds_read_b128 %0, %1" : "=v"(r) : "v"(a));
  return r;
}

// ---------------- prep: router (+x->f16) AND weight transposes, fused ----------------

__global__ __launch_bounds__(256) void prep_kernel(
    const float* __restrict__ x, const float* __restrict__ Wr,
    const float* __restrict__ br, const float* __restrict__ Wg,
    const float* __restrict__ Wu, const float* __restrict__ Wd,
    int* __restrict__ eidx, float2* __restrict__ pval,
    int* __restrict__ counts, f16* __restrict__ xb,
    f16* __restrict__ wgut, f16* __restrict__ wdt) {
  __shared__ float tile[128][33];
  int g = blockIdx.x;
  if (g < T_TOK / 4) {
    // ---- router part ----
    int lane = threadIdx.x & 63, wid = threadIdx.x >> 6;
    int t = g * 4 + wid;
    const float* xr = x + (size_t)t * D_IN;
    float s[8] = {0.f, 0.f, 0.f, 0.f, 0.f, 0.f, 0.f, 0.f};
    int dbase = lane * 16;
#pragma unroll
    for (int i = 0; i < 4; ++i) {
      float4 xv = *(const float4*)(xr + dbase + i * 4);
      f16x4 xo = {(f16)xv.x, (f16)xv.y, (f16)xv.z, (f16)xv.w};
      *(f16x4*)(xb + (size_t)t * D_IN + dbase + i * 4) = xo;
      const float xs[4] = {xv.x, xv.y, xv.z, xv.w};
#pragma unroll
      for (int j = 0; j < 4; ++j) {
        const float* wr = Wr + (size_t)(dbase + i * 4 + j) * E_EXP;
        float4 w0 = *(const float4*)wr;
        float4 w1 = *(const float4*)(wr + 4);
        float xvj = xs[j];
        s[0] += xvj * w0.x; s[1] += xvj * w0.y; s[2] += xvj * w0.z; s[3] += xvj * w0.w;
        s[4] += xvj * w1.x; s[5] += xvj * w1.y; s[6] += xvj * w1.z; s[7] += xvj * w1.w;
      }
    }
#pragma unroll
    for (int off = 32; off; off >>= 1)
#pragma unroll
      for (int e = 0; e < 8; ++e) s[e] += __shfl_xor(s[e], off);
    if (lane == 0) {
      float v[8];
#pragma unroll
      for (int e = 0; e < 8; ++e) v[e] = s[e] + br[e];
      int i0 = 0; float v0 = v[0];
#pragma unroll
      for (int e = 1; e < 8; ++e) if (v[e] > v0) { v0 = v[e]; i0 = e; }
      int i1 = -1; float v1 = -1e30f;
#pragma unroll
      for (int e = 0; e < 8; ++e)
        if (e != i0 && v[e] > v1) { v1 = v[e]; i1 = e; }
      float ed = __expf(v1 - v0);
      float inv = 1.f / (1.f + ed);
      eidx[t] = i0 | (i1 << 8);
      pval[t] = make_float2(inv, ed * inv);
      atomicAdd(&counts[i0], 1);
      atomicAdd(&counts[i1], 1);
    }
    return;
  }
  // ---- transpose part ----
  int i = g - T_TOK / 4;
  int which = i >> 13;          // 0=Wg, 1=Wu, 2=Wd
  int j = i & 8191;
  const float* src; f16* dst; int R, C, MAP, cx, cy, e; size_t dstride;
  if (which < 2) {
    cx = j & 127; cy = (j >> 7) & 7; e = j >> 10;
    R = D_IN; C = H_HID; dstride = (size_t)2 * H_HID * D_IN;
    dst = wgut; src = (which == 0) ? Wg : Wu; MAP = which + 1;
  } else {
    cx = j & 31; cy = (j >> 5) & 31; e = j >> 10;
    R = H_HID; C = D_IN; dstride = (size_t)D_IN * H_HID;
    dst = wdt; src = Wd; MAP = 0;
  }
  const float* s = src + (size_t)e * R * C;
  f16* d = dst + (size_t)e * dstride;
  int c0 = cx * 32, r0 = cy * 128;
#pragma unroll
  for (int q4 = 0; q4 < 4; ++q4) {
    int q = q4 * 256 + threadIdx.x;
    int r = q >> 3, c4 = (q & 7) * 4;
    float4 v = *(const float4*)(s + (size_t)(r0 + r) * C + c0 + c4);
    tile[r][c4 + 0] = v.x; tile[r][c4 + 1] = v.y;
    tile[r][c4 + 2] = v.z; tile[r][c4 + 3] = v.w;
  }
  __syncthreads();
#pragma unroll
  for (int w2 = 0; w2 < 2; ++w2) {
    int w = w2 * 256 + threadIdx.x;
    int col = w >> 4, oct = w & 15;
    int c = c0 + col;
    int ro = (MAP == 0) ? c : (((c >> 4) << 5) + ((MAP == 2) ? 16 : 0) + (c & 15));
    f16x8 o;
#pragma unroll
    for (int k = 0; k < 8; ++k) o[k] = (f16)tile[oct * 8 + k][col];
    *(f16x8*)(d + (size_t)ro * R + r0 + oct * 8) = o;
  }
}

__global__ void scan_kernel(const int* __restrict__ counts, int* __restrict__ offsets) {
  if (threadIdx.x == 0) {
    int acc = 0;
#pragma unroll
    for (int e = 0; e < E_EXP; ++e) { offsets[e] = acc; acc += counts[e]; }
    offsets[E_EXP] = acc;
  }
}

__global__ __launch_bounds__(256) void scatter_kernel(
    const int* __restrict__ eidx, const float2* __restrict__ pval,
    const int* __restrict__ offsets, int* __restrict__ cursors,
    int* __restrict__ perm, float* __restrict__ gatew, int2* __restrict__ slotAB) {
  int t = blockIdx.x * 256 + threadIdx.x;
  if (t >= T_TOK) return;
  int ei = eidx[t];
  float2 p = pval[t];
  int e0 = ei & 0xff, e1 = (ei >> 8) & 0xff;
  int s0 = offsets[e0] + atomicAdd(&cursors[e0], 1);
  perm[s0] = t; gatew[s0] = p.x;
  int s1 = offsets[e1] + atomicAdd(&cursors[e1], 1);
  perm[s1] = t; gatew[s1] = p.y;
  slotAB[t] = make_int2(s0, s1);
}

// ---------------- 8-phase 256x256 grouped GEMM ----------------
// R8 schedule; R12 repack epilogue; R15 asm ds_reads + explicit
// lgkmcnt(0)+sched_barrier(0) after each opening barrier (rule #18).

#define BAR __builtin_amdgcn_s_barrier()
#define VMCNT(N) asm volatile("s_waitcnt vmcnt(" #N ")" ::: "memory")
#define LGKM0 do {                                           \
  asm volatile("s_waitcnt lgkmcnt(0)" ::: "memory");         \
  __builtin_amdgcn_sched_barrier(0);                         \
} while (0)

#define STAGE_(B, ISB, H, KT, BASE) do {                                   \
  char* d_ = smem + (B)*65536 + (ISB)*32768 + (H)*16384 + wid*1024;        \
  gload_lds16(BASE[(H)*2+0] + (size_t)(KT)*64, d_);                        \
  gload_lds16(BASE[(H)*2+1] + (size_t)(KT)*64, d_ + 8192);                 \
} while (0)

#define LDA_(B, Q)                                                          \
  _Pragma("unroll")                                                         \
  for (int m_ = 0; m_ < 4; ++m_) {                                          \
    fa[m_][0] = dsrd(smem + (B)*65536 + aoff + ((Q)*4+m_)*2048 + offk0);    \
    fa[m_][1] = dsrd(smem + (B)*65536 + aoff + ((Q)*4+m_)*2048 + offk1);    \
  }

#define LDB_(FB, B, RH)                                                     \
  _Pragma("unroll")                                                         \
  for (int n_ = 0; n_ < 2; ++n_) {                                          \
    FB[n_][0] = dsrd(smem + (B)*65536 + 32768 + boff + ((RH)*2+n_)*2048 + offk0); \
    FB[n_][1] = dsrd(smem + (B)*65536 + 32768 + boff + ((RH)*2+n_)*2048 + offk1); \
  }

#define QUAD_(Q, RH, FB)                                                    \
  __builtin_amdgcn_s_setprio(1);                                            \
  _Pragma("unroll")                                                         \
  for (int m_ = 0; m_ < 4; ++m_)                                            \
    _Pragma("unroll")                                                       \
    for (int n_ = 0; n_ < 2; ++n_) {                                        \
      acc[(Q)*4+m_][(RH)*2+n_] = __builtin_amdgcn_mfma_f32_16x16x32_f16(    \
          fa[m_][0], FB[n_][0], acc[(Q)*4+m_][(RH)*2+n_], 0, 0, 0);         \
      acc[(Q)*4+m_][(RH)*2+n_] = __builtin_amdgcn_mfma_f32_16x16x32_f16(    \
          fa[m_][1], FB[n_][1], acc[(Q)*4+m_][(RH)*2+n_], 0, 0, 0);         \
    }                                                                       \
  __builtin_amdgcn_s_setprio(0);

template<int MODE>
__global__ __launch_bounds__(512, 2) void ffn_8ph_kernel(
    const f16* __restrict__ Asrc, const f16* __restrict__ Bsrc,
    const float* __restrict__ bias0, const float* __restrict__ bias1,
    const int* __restrict__ offsets, const int* __restrict__ perm,
    const float* __restrict__ gatew, f16* __restrict__ dst) {
  constexpr int KD = MODE ? H_HID : D_IN;
  constexpr int BROWS = MODE ? D_IN : 2 * H_HID;
  constexpr int NT = 16;

  __shared__ __align__(16) char smem[131072];

  int g = blockIdx.x;
  int xcd = g & 7;
  int mt = (g >> 3) & 31;
  int e, nt, kc;
  if constexpr (MODE == 0) {
    int panel = xcd + 8 * (g >> 8);   // [0,256)
    e = panel >> 5; nt = panel & 31; kc = 0;
  } else {
    int sp = xcd + 8 * (g >> 8);      // [0,128)
    e = sp >> 4; nt = (sp >> 2) & 3; kc = sp & 3;
  }

  int off = offsets[e];
  int cnt = offsets[e + 1] - off;
  if (mt * 256 >= cnt) return;

  int tid = threadIdx.x, lane = tid & 63, wid = tid >> 6;
  int wm = wid >> 2, wn = wid & 3;
  int l15 = lane & 15, lc0 = lane >> 4, s7 = l15 & 7;
  int aoff = (wm * 128 + l15) * 128;
  int boff = (wn * 64 + l15) * 128;
  int offk0 = ((lc0) ^ s7) * 16;
  int offk1 = ((lc0 + 4) ^ s7) * 16;

  int rowh_[2], lc_[2];
#pragma unroll
  for (int i = 0; i < 2; ++i) {
    int chunk = (i * 8 + wid) * 64 + lane;
    rowh_[i] = chunk >> 3;
    lc_[i] = (chunk & 7) ^ (rowh_[i] & 7);
  }

  const f16 *aB[4], *bB[4];
#pragma unroll
  for (int h = 0; h < 2; ++h)
#pragma unroll
    for (int i = 0; i < 2; ++i) {
      int absrow = h * 128 + rowh_[i];
      bB[h * 2 + i] = Bsrc + ((size_t)e * BROWS + nt * 256 + absrow) * KD +
                      kc * 1024 + lc_[i] * 8;
      int slot = off + min(mt * 256 + absrow, cnt - 1);
      if constexpr (MODE == 0)
        aB[h * 2 + i] = Asrc + (size_t)perm[slot] * KD + lc_[i] * 8;
      else
        aB[h * 2 + i] = Asrc + (size_t)slot * KD + kc * 1024 + lc_[i] * 8;
    }

  float bv0[4], bv1[2];
  if constexpr (MODE == 0) {
#pragma unroll
    for (int p = 0; p < 2; ++p) {
      int h = nt * 128 + wn * 32 + p * 16 + l15;
      bv0[p] = bias0[e * H_HID + h];
      bv1[p] = bias1[e * H_HID + h];
    }
  } else {
#pragma unroll
    for (int n = 0; n < 4; ++n)
      bv0[n] = (kc == 0)
                   ? bias0[e * D_IN + nt * 256 + wn * 64 + n * 16 + l15]
                   : 0.f;
  }

  f32x4 acc[8][4] = {};
  f16x8 fa[4][2], fb01[2][2], fb23[2][2];

  // prologue: buf0.B, buf0.A (t0); buf1.B (t1); buf1.A-H0 (t1) — 14 loads.
  STAGE_(0, 1, 0, 0, bB); STAGE_(0, 1, 1, 0, bB);
  STAGE_(0, 0, 0, 0, aB); STAGE_(0, 0, 1, 0, aB);
  STAGE_(1, 1, 0, 1, bB); STAGE_(1, 1, 1, 1, bB);
  STAGE_(1, 0, 0, 1, aB);
  VMCNT(6);
  BAR;

  for (int it = 0; it < NT / 2; ++it) {
    int b_ = 2 * it + 1;
    int a2 = min(2 * it + 2, NT - 1);
    int b2 = min(2 * it + 3, NT - 1);
    // P1
    LDA_(0, 0); LDB_(fb01, 0, 0); STAGE_(1, 0, 1, b_, aB);
    BAR; LGKM0; QUAD_(0, 0, fb01); BAR;
    // P2
    LDB_(fb23, 0, 1);
    BAR; LGKM0; QUAD_(0, 1, fb23); BAR;
    // P3
    LDA_(0, 1); STAGE_(0, 1, 0, a2, bB);
    BAR; LGKM0; QUAD_(1, 0, fb01); BAR;
    // P4
    STAGE_(0, 1, 1, a2, bB);
    BAR; LGKM0; QUAD_(1, 1, fb23);
    VMCNT(4);
    BAR;
    // P5
    LDA_(1, 0); LDB_(fb01, 1, 0); STAGE_(0, 0, 0, a2, aB);
    BAR; LGKM0; QUAD_(0, 0, fb01); BAR;
    // P6
    LDB_(fb23, 1, 1); STAGE_(0, 0, 1, a2, aB);
    BAR; LGKM0; QUAD_(0, 1, fb23); BAR;
    // P7
    LDA_(1, 1); STAGE_(1, 1, 0, b2, bB);
    BAR; LGKM0; QUAD_(1, 0, fb01); BAR;
    // P8
    STAGE_(1, 1, 1, b2, bB); STAGE_(1, 0, 0, b2, aB);
    BAR; LGKM0; QUAD_(1, 1, fb23);
    VMCNT(6);
    BAR;
  }

  // drain ALL staging loads before reusing LDS for the repack tile
  VMCNT(0);
  __syncthreads();

  int c0_ = lc0 * 4;
  f16* tile = (f16*)smem;
  if constexpr (MODE == 0) {
    // repack: [256][128] f16 (64KB)
#pragma unroll
    for (int p = 0; p < 2; ++p) {
      int colL = wn * 32 + p * 16 + l15;
#pragma unroll
      for (int m = 0; m < 8; ++m) {
        int row = wm * 128 + m * 16 + c0_;
#pragma unroll
        for (int r = 0; r < 4; ++r) {
          float gv = acc[m][2 * p][r] + bv0[p];
          float uv = acc[m][2 * p + 1][r] + bv1[p];
          tile[(row + r) * 128 + colL] = (f16)((gv / (1.f + __expf(-gv))) * uv);
        }
      }
    }
    __syncthreads();
    f16* dbase = dst + (size_t)(off + mt * 256) * H_HID + nt * 128;
#pragma unroll
    for (int i = 0; i < 8; ++i) {
      int linear = i * 512 + tid;
      int row = linear >> 4, c16 = linear & 15;
      if (mt * 256 + row < cnt) {
        f16x8 v = *(const f16x8*)&tile[row * 128 + c16 * 8];
        __builtin_nontemporal_store(v, (f16x8*)(dbase + (size_t)row * H_HID + c16 * 8));
      }
    }
  } else {
    // repack: [256][256] f16 (128KB)
#pragma unroll
    for (int n = 0; n < 4; ++n) {
      int colL = wn * 64 + n * 16 + l15;
#pragma unroll
      for (int m = 0; m < 8; ++m) {
        int row = wm * 128 + m * 16 + c0_;
#pragma unroll
        for (int r = 0; r < 4; ++r) {
          int slot = off + min(mt * 256 + row + r, cnt - 1);
          tile[(row + r) * 256 + colL] =
              (f16)(gatew[slot] * (acc[m][n][r] + bv0[n]));
        }
      }
    }
    __syncthreads();
    f16* dstP = dst + (size_t)kc * NSLOT_PAD * D_IN;
    f16* dbase = dstP + (size_t)(off + mt * 256) * D_IN + nt * 256;
#pragma unroll
    for (int i = 0; i < 16; ++i) {
      int linear = i * 512 + tid;
      int row = linear >> 5, c16 = linear & 31;
      if (mt * 256 + row < cnt) {
        f16x8 v = *(const f16x8*)&tile[row * 256 + c16 * 8];
        __builtin_nontemporal_store(v, (f16x8*)(dbase + (size_t)row * D_IN + c16 * 8));
      }
    }
  }
}

// ------- combine: out[t] = sum over s in {s0,s1}, kc in [0,4) of partial -------
__global__ __launch_bounds__(256) void combine_kernel(
    const f16* __restrict__ ypart, const int2* __restrict__ slotAB,
    float* __restrict__ out) {
  int i = blockIdx.x * 256 + threadIdx.x;
  int t = i >> 7;
  int c8 = i & 127;
  int2 s = slotAB[t];
  float sum[8] = {0.f, 0.f, 0.f, 0.f, 0.f, 0.f, 0.f, 0.f};
#pragma unroll
  for (int kc = 0; kc < KSPLIT; ++kc) {
    const f16* base = ypart + (size_t)kc * NSLOT_PAD * D_IN + c8 * 8;
    f16x8 y0 = *(const f16x8*)(base + (size_t)s.x * D_IN);
    f16x8 y1 = *(const f16x8*)(base + (size_t)s.y * D_IN);
#pragma unroll
    for (int j = 0; j < 8; ++j) sum[j] += (float)y0[j] + (float)y1[j];
  }
  float* o = out + (size_t)t * D_IN + c8 * 8;
  f32x4 o0 = {sum[0], sum[1], sum[2], sum[3]};
  f32x4 o1 = {sum[4], sum[5], sum[6], sum[7]};
  __builtin_nontemporal_store(o0, (f32x4*)o);
  __builtin_nontemporal_store(o1, (f32x4*)(o + 4));
}

// ---------------- launch ----------------

extern "C" void kernel_launch(void* const* d_in, const int* in_sizes, int n_in,
                              void* d_out, int out_size, void* d_ws, size_t ws_size,
                              hipStream_t stream) {
  const float* x  = (const float*)d_in[0];
  const float* Wr = (const float*)d_in[1];
  const float* br = (const float*)d_in[2];
  const float* Wg = (const float*)d_in[3];
  const float* bg = (const float*)d_in[4];
  const float* Wu = (const float*)d_in[5];
  const float* bu = (const float*)d_in[6];
  const float* Wd = (const float*)d_in[7];
  const float* bd = (const float*)d_in[8];
  float* out = (float*)d_out;

  char* ws = (char*)d_ws;
  size_t o = 0;
  auto alloc = [&](size_t bytes) {
    size_t r = o;
    o += (bytes + 255) & ~(size_t)255;
    return r;
  };
  f16* xb     = (f16*)(ws + alloc((size_t)T_TOK * D_IN * 2));               // 16MB
  f16* wgut   = (f16*)(ws + alloc((size_t)E_EXP * 2 * H_HID * D_IN * 2));   // 128MB
  f16* wdt    = (f16*)(ws + alloc((size_t)E_EXP * D_IN * H_HID * 2));       // 64MB
  f16* hbuf   = (f16*)(ws + alloc((size_t)NSLOT_PAD * H_HID * 2));          // 135MB
  int* eidx   = (int*)(ws + alloc((size_t)T_TOK * 4));
  float2* pval= (float2*)(ws + alloc((size_t)T_TOK * 8));
  int* counts = (int*)(ws + alloc(64 * 4));
  int* cursors = counts + 8;
  int* offsets = counts + 16;
  int* perm   = (int*)(ws + alloc((size_t)NSLOT_PAD * 4));
  float* gatew= (float*)(ws + alloc((size_t)NSLOT_PAD * 4));
  int2* slotAB= (int2*)(ws + alloc((size_t)T_TOK * 8));
  // ypart aliases xb+wgut (both dead after ffn1): 4*34MB = 136MB <= 144MB.
  f16* ypart  = xb;

  hipMemsetAsync(counts, 0, 64 * 4, stream);

  // prep: router (2048 blocks) + Wg/Wu/Wd transposes (3 x 8192 blocks)
  prep_kernel<<<dim3(T_TOK / 4 + 3 * 8192), 256, 0, stream>>>(
      x, Wr, br, Wg, Wu, Wd, eidx, pval, counts, xb, wgut, wdt);
  scan_kernel<<<1, 64, 0, stream>>>(counts, offsets);
  scatter_kernel<<<T_TOK / 256, 256, 0, stream>>>(eidx, pval, offsets, cursors,
                                                  perm, gatew, slotAB);
  // FFN1: 8192 blocks, XCD-panel affinity.
  ffn_8ph_kernel<0><<<dim3(8192), 512, 0, stream>>>(
      xb, wgut, bg, bu, offsets, perm, nullptr, hbuf);
  // FFN2: 4096 blocks, split-K=4, disjoint f16 partials (no atomics).
  ffn_8ph_kernel<1><<<dim3(4096), 512, 0, stream>>>(
      hbuf, wdt, bd, nullptr, offsets, nullptr, gatew, ypart);
  combine_kernel<<<T_TOK * D_IN / 8 / 256, 256, 0, stream>>>(ypart, slotAB, out);
}

// Round 16
// 931.970 us; speedup vs baseline: 1.2510x; 1.2510x over previous
//
#include <hip/hip_runtime.h>
#include <hip/hip_fp16.h>

// MoE: B=4 S=2048 D=1024 E=8 K=2 H=4096. T=8192 tokens, 16384 assignments.
// R16: revert R15 (asm ds_read serialized reads + spills: 364->520us).
// Base = R14 champion (912us). One change: hbuf/ypart producer stores are
// now REGULAR (L3-allocating) -- they are consumed by the next kernel and
// fit L3 (135/136MB < 256MB). R5's nontemporal was to protect wgut L3
// residency, obsolete since R6 moved B-locality to per-XCD L2. `out` stays
// nontemporal (never re-read).

#define T_TOK 8192
#define D_IN  1024
#define E_EXP 8
#define H_HID 4096
#define NSLOT (T_TOK * 2)
#define NSLOT_PAD (NSLOT + 256)
#define KSPLIT 4

typedef _Float16 f16;
typedef __attribute__((ext_vector_type(8))) _Float16 f16x8;
typedef __attribute__((ext_vector_type(4))) _Float16 f16x4;
typedef __attribute__((ext_vector_type(4))) float f32x4;

__device__ __forceinline__ void gload_lds16(const void* g, void* l) {
  __builtin_amdgcn_global_load_lds(
      (const __attribute__((address_space(1))) unsigned int*)g,
      (__attribute__((address_space(3))) unsigned int*)l, 16, 0, 0);
}

// ---------------- prep: router (+x->f16) AND weight transposes, fused ----------------

__global__ __launch_bounds__(256) void prep_kernel(
    const float* __restrict__ x, const float* __restrict__ Wr,
    const float* __restrict__ br, const float* __restrict__ Wg,
    const float* __restrict__ Wu, const float* __restrict__ Wd,
    int* __restrict__ eidx, float2* __restrict__ pval,
    int* __restrict__ counts, f16* __restrict__ xb,
    f16* __restrict__ wgut, f16* __restrict__ wdt) {
  __shared__ float tile[128][33];
  int g = blockIdx.x;
  if (g < T_TOK / 4) {
    // ---- router part ----
    int lane = threadIdx.x & 63, wid = threadIdx.x >> 6;
    int t = g * 4 + wid;
    const float* xr = x + (size_t)t * D_IN;
    float s[8] = {0.f, 0.f, 0.f, 0.f, 0.f, 0.f, 0.f, 0.f};
    int dbase = lane * 16;
#pragma unroll
    for (int i = 0; i < 4; ++i) {
      float4 xv = *(const float4*)(xr + dbase + i * 4);
      f16x4 xo = {(f16)xv.x, (f16)xv.y, (f16)xv.z, (f16)xv.w};
      *(f16x4*)(xb + (size_t)t * D_IN + dbase + i * 4) = xo;
      const float xs[4] = {xv.x, xv.y, xv.z, xv.w};
#pragma unroll
      for (int j = 0; j < 4; ++j) {
        const float* wr = Wr + (size_t)(dbase + i * 4 + j) * E_EXP;
        float4 w0 = *(const float4*)wr;
        float4 w1 = *(const float4*)(wr + 4);
        float xvj = xs[j];
        s[0] += xvj * w0.x; s[1] += xvj * w0.y; s[2] += xvj * w0.z; s[3] += xvj * w0.w;
        s[4] += xvj * w1.x; s[5] += xvj * w1.y; s[6] += xvj * w1.z; s[7] += xvj * w1.w;
      }
    }
#pragma unroll
    for (int off = 32; off; off >>= 1)
#pragma unroll
      for (int e = 0; e < 8; ++e) s[e] += __shfl_xor(s[e], off);
    if (lane == 0) {
      float v[8];
#pragma unroll
      for (int e = 0; e < 8; ++e) v[e] = s[e] + br[e];
      int i0 = 0; float v0 = v[0];
#pragma unroll
      for (int e = 1; e < 8; ++e) if (v[e] > v0) { v0 = v[e]; i0 = e; }
      int i1 = -1; float v1 = -1e30f;
#pragma unroll
      for (int e = 0; e < 8; ++e)
        if (e != i0 && v[e] > v1) { v1 = v[e]; i1 = e; }
      float ed = __expf(v1 - v0);
      float inv = 1.f / (1.f + ed);
      eidx[t] = i0 | (i1 << 8);
      pval[t] = make_float2(inv, ed * inv);
      atomicAdd(&counts[i0], 1);
      atomicAdd(&counts[i1], 1);
    }
    return;
  }
  // ---- transpose part ----
  int i = g - T_TOK / 4;
  int which = i >> 13;          // 0=Wg, 1=Wu, 2=Wd
  int j = i & 8191;
  const float* src; f16* dst; int R, C, MAP, cx, cy, e; size_t dstride;
  if (which < 2) {
    cx = j & 127; cy = (j >> 7) & 7; e = j >> 10;
    R = D_IN; C = H_HID; dstride = (size_t)2 * H_HID * D_IN;
    dst = wgut; src = (which == 0) ? Wg : Wu; MAP = which + 1;
  } else {
    cx = j & 31; cy = (j >> 5) & 31; e = j >> 10;
    R = H_HID; C = D_IN; dstride = (size_t)D_IN * H_HID;
    dst = wdt; src = Wd; MAP = 0;
  }
  const float* s = src + (size_t)e * R * C;
  f16* d = dst + (size_t)e * dstride;
  int c0 = cx * 32, r0 = cy * 128;
#pragma unroll
  for (int q4 = 0; q4 < 4; ++q4) {
    int q = q4 * 256 + threadIdx.x;
    int r = q >> 3, c4 = (q & 7) * 4;
    float4 v = *(const float4*)(s + (size_t)(r0 + r) * C + c0 + c4);
    tile[r][c4 + 0] = v.x; tile[r][c4 + 1] = v.y;
    tile[r][c4 + 2] = v.z; tile[r][c4 + 3] = v.w;
  }
  __syncthreads();
#pragma unroll
  for (int w2 = 0; w2 < 2; ++w2) {
    int w = w2 * 256 + threadIdx.x;
    int col = w >> 4, oct = w & 15;
    int c = c0 + col;
    int ro = (MAP == 0) ? c : (((c >> 4) << 5) + ((MAP == 2) ? 16 : 0) + (c & 15));
    f16x8 o;
#pragma unroll
    for (int k = 0; k < 8; ++k) o[k] = (f16)tile[oct * 8 + k][col];
    *(f16x8*)(d + (size_t)ro * R + r0 + oct * 8) = o;
  }
}

__global__ void scan_kernel(const int* __restrict__ counts, int* __restrict__ offsets) {
  if (threadIdx.x == 0) {
    int acc = 0;
#pragma unroll
    for (int e = 0; e < E_EXP; ++e) { offsets[e] = acc; acc += counts[e]; }
    offsets[E_EXP] = acc;
  }
}

__global__ __launch_bounds__(256) void scatter_kernel(
    const int* __restrict__ eidx, const float2* __restrict__ pval,
    const int* __restrict__ offsets, int* __restrict__ cursors,
    int* __restrict__ perm, float* __restrict__ gatew, int2* __restrict__ slotAB) {
  int t = blockIdx.x * 256 + threadIdx.x;
  if (t >= T_TOK) return;
  int ei = eidx[t];
  float2 p = pval[t];
  int e0 = ei & 0xff, e1 = (ei >> 8) & 0xff;
  int s0 = offsets[e0] + atomicAdd(&cursors[e0], 1);
  perm[s0] = t; gatew[s0] = p.x;
  int s1 = offsets[e1] + atomicAdd(&cursors[e1], 1);
  perm[s1] = t; gatew[s1] = p.y;
  slotAB[t] = make_int2(s0, s1);
}

// ---------------- 8-phase 256x256 grouped GEMM ----------------
// R8 schedule; R12 repack epilogue; R14 bare-s_barrier; R16 L3-allocating
// producer stores (hbuf/ypart are consumed by the next kernel).

#define BAR __builtin_amdgcn_s_barrier()
#define VMCNT(N) asm volatile("s_waitcnt vmcnt(" #N ")" ::: "memory")

#define STAGE_(B, ISB, H, KT, BASE) do {                                   \
  char* d_ = smem + (B)*65536 + (ISB)*32768 + (H)*16384 + wid*1024;        \
  gload_lds16(BASE[(H)*2+0] + (size_t)(KT)*64, d_);                        \
  gload_lds16(BASE[(H)*2+1] + (size_t)(KT)*64, d_ + 8192);                 \
} while (0)

#define LDA_(B, Q)                                                          \
  _Pragma("unroll")                                                         \
  for (int m_ = 0; m_ < 4; ++m_) {                                          \
    fa[m_][0] = *(const f16x8*)(smem + (B)*65536 + aoff + ((Q)*4+m_)*2048 + offk0); \
    fa[m_][1] = *(const f16x8*)(smem + (B)*65536 + aoff + ((Q)*4+m_)*2048 + offk1); \
  }

#define LDB_(FB, B, RH)                                                     \
  _Pragma("unroll")                                                         \
  for (int n_ = 0; n_ < 2; ++n_) {                                          \
    FB[n_][0] = *(const f16x8*)(smem + (B)*65536 + 32768 + boff + ((RH)*2+n_)*2048 + offk0); \
    FB[n_][1] = *(const f16x8*)(smem + (B)*65536 + 32768 + boff + ((RH)*2+n_)*2048 + offk1); \
  }

#define QUAD_(Q, RH, FB)                                                    \
  __builtin_amdgcn_s_setprio(1);                                            \
  _Pragma("unroll")                                                         \
  for (int m_ = 0; m_ < 4; ++m_)                                            \
    _Pragma("unroll")                                                       \
    for (int n_ = 0; n_ < 2; ++n_) {                                        \
      acc[(Q)*4+m_][(RH)*2+n_] = __builtin_amdgcn_mfma_f32_16x16x32_f16(    \
          fa[m_][0], FB[n_][0], acc[(Q)*4+m_][(RH)*2+n_], 0, 0, 0);         \
      acc[(Q)*4+m_][(RH)*2+n_] = __builtin_amdgcn_mfma_f32_16x16x32_f16(    \
          fa[m_][1], FB[n_][1], acc[(Q)*4+m_][(RH)*2+n_], 0, 0, 0);         \
    }                                                                       \
  __builtin_amdgcn_s_setprio(0);

template<int MODE>
__global__ __launch_bounds__(512, 2) void ffn_8ph_kernel(
    const f16* __restrict__ Asrc, const f16* __restrict__ Bsrc,
    const float* __restrict__ bias0, const float* __restrict__ bias1,
    const int* __restrict__ offsets, const int* __restrict__ perm,
    const float* __restrict__ gatew, f16* __restrict__ dst) {
  constexpr int KD = MODE ? H_HID : D_IN;
  constexpr int BROWS = MODE ? D_IN : 2 * H_HID;
  constexpr int NT = 16;

  __shared__ __align__(16) char smem[131072];

  int g = blockIdx.x;
  int xcd = g & 7;
  int mt = (g >> 3) & 31;
  int e, nt, kc;
  if constexpr (MODE == 0) {
    int panel = xcd + 8 * (g >> 8);   // [0,256)
    e = panel >> 5; nt = panel & 31; kc = 0;
  } else {
    int sp = xcd + 8 * (g >> 8);      // [0,128)
    e = sp >> 4; nt = (sp >> 2) & 3; kc = sp & 3;
  }

  int off = offsets[e];
  int cnt = offsets[e + 1] - off;
  if (mt * 256 >= cnt) return;

  int tid = threadIdx.x, lane = tid & 63, wid = tid >> 6;
  int wm = wid >> 2, wn = wid & 3;
  int l15 = lane & 15, lc0 = lane >> 4, s7 = l15 & 7;
  int aoff = (wm * 128 + l15) * 128;
  int boff = (wn * 64 + l15) * 128;
  int offk0 = ((lc0) ^ s7) * 16;
  int offk1 = ((lc0 + 4) ^ s7) * 16;

  int rowh_[2], lc_[2];
#pragma unroll
  for (int i = 0; i < 2; ++i) {
    int chunk = (i * 8 + wid) * 64 + lane;
    rowh_[i] = chunk >> 3;
    lc_[i] = (chunk & 7) ^ (rowh_[i] & 7);
  }

  const f16 *aB[4], *bB[4];
#pragma unroll
  for (int h = 0; h < 2; ++h)
#pragma unroll
    for (int i = 0; i < 2; ++i) {
      int absrow = h * 128 + rowh_[i];
      bB[h * 2 + i] = Bsrc + ((size_t)e * BROWS + nt * 256 + absrow) * KD +
                      kc * 1024 + lc_[i] * 8;
      int slot = off + min(mt * 256 + absrow, cnt - 1);
      if constexpr (MODE == 0)
        aB[h * 2 + i] = Asrc + (size_t)perm[slot] * KD + lc_[i] * 8;
      else
        aB[h * 2 + i] = Asrc + (size_t)slot * KD + kc * 1024 + lc_[i] * 8;
    }

  float bv0[4], bv1[2];
  if constexpr (MODE == 0) {
#pragma unroll
    for (int p = 0; p < 2; ++p) {
      int h = nt * 128 + wn * 32 + p * 16 + l15;
      bv0[p] = bias0[e * H_HID + h];
      bv1[p] = bias1[e * H_HID + h];
    }
  } else {
#pragma unroll
    for (int n = 0; n < 4; ++n)
      bv0[n] = (kc == 0)
                   ? bias0[e * D_IN + nt * 256 + wn * 64 + n * 16 + l15]
                   : 0.f;
  }

  f32x4 acc[8][4] = {};
  f16x8 fa[4][2], fb01[2][2], fb23[2][2];

  // prologue: buf0.B, buf0.A (t0); buf1.B (t1); buf1.A-H0 (t1) — 14 loads.
  STAGE_(0, 1, 0, 0, bB); STAGE_(0, 1, 1, 0, bB);
  STAGE_(0, 0, 0, 0, aB); STAGE_(0, 0, 1, 0, aB);
  STAGE_(1, 1, 0, 1, bB); STAGE_(1, 1, 1, 1, bB);
  STAGE_(1, 0, 0, 1, aB);
  VMCNT(6);
  BAR;

  for (int it = 0; it < NT / 2; ++it) {
    int b_ = 2 * it + 1;
    int a2 = min(2 * it + 2, NT - 1);
    int b2 = min(2 * it + 3, NT - 1);
    // P1
    LDA_(0, 0); LDB_(fb01, 0, 0); STAGE_(1, 0, 1, b_, aB);
    BAR; QUAD_(0, 0, fb01); BAR;
    // P2
    LDB_(fb23, 0, 1);
    BAR; QUAD_(0, 1, fb23); BAR;
    // P3
    LDA_(0, 1); STAGE_(0, 1, 0, a2, bB);
    BAR; QUAD_(1, 0, fb01); BAR;
    // P4
    STAGE_(0, 1, 1, a2, bB);
    BAR; QUAD_(1, 1, fb23);
    VMCNT(4);
    BAR;
    // P5
    LDA_(1, 0); LDB_(fb01, 1, 0); STAGE_(0, 0, 0, a2, aB);
    BAR; QUAD_(0, 0, fb01); BAR;
    // P6
    LDB_(fb23, 1, 1); STAGE_(0, 0, 1, a2, aB);
    BAR; QUAD_(0, 1, fb23); BAR;
    // P7
    LDA_(1, 1); STAGE_(1, 1, 0, b2, bB);
    BAR; QUAD_(1, 0, fb01); BAR;
    // P8
    STAGE_(1, 1, 1, b2, bB); STAGE_(1, 0, 0, b2, aB);
    BAR; QUAD_(1, 1, fb23);
    VMCNT(6);
    BAR;
  }

  // drain ALL staging loads before reusing LDS for the repack tile
  VMCNT(0);
  __syncthreads();

  int c0_ = lc0 * 4;
  f16* tile = (f16*)smem;
  if constexpr (MODE == 0) {
    // repack: [256][128] f16 (64KB)
#pragma unroll
    for (int p = 0; p < 2; ++p) {
      int colL = wn * 32 + p * 16 + l15;
#pragma unroll
      for (int m = 0; m < 8; ++m) {
        int row = wm * 128 + m * 16 + c0_;
#pragma unroll
        for (int r = 0; r < 4; ++r) {
          float gv = acc[m][2 * p][r] + bv0[p];
          float uv = acc[m][2 * p + 1][r] + bv1[p];
          tile[(row + r) * 128 + colL] = (f16)((gv / (1.f + __expf(-gv))) * uv);
        }
      }
    }
    __syncthreads();
    f16* dbase = dst + (size_t)(off + mt * 256) * H_HID + nt * 128;
#pragma unroll
    for (int i = 0; i < 8; ++i) {
      int linear = i * 512 + tid;
      int row = linear >> 4, c16 = linear & 15;
      if (mt * 256 + row < cnt) {
        f16x8 v = *(const f16x8*)&tile[row * 128 + c16 * 8];
        *(f16x8*)(dbase + (size_t)row * H_HID + c16 * 8) = v;  // L3-allocate
      }
    }
  } else {
    // repack: [256][256] f16 (128KB)
#pragma unroll
    for (int n = 0; n < 4; ++n) {
      int colL = wn * 64 + n * 16 + l15;
#pragma unroll
      for (int m = 0; m < 8; ++m) {
        int row = wm * 128 + m * 16 + c0_;
#pragma unroll
        for (int r = 0; r < 4; ++r) {
          int slot = off + min(mt * 256 + row + r, cnt - 1);
          tile[(row + r) * 256 + colL] =
              (f16)(gatew[slot] * (acc[m][n][r] + bv0[n]));
        }
      }
    }
    __syncthreads();
    f16* dstP = dst + (size_t)kc * NSLOT_PAD * D_IN;
    f16* dbase = dstP + (size_t)(off + mt * 256) * D_IN + nt * 256;
#pragma unroll
    for (int i = 0; i < 16; ++i) {
      int linear = i * 512 + tid;
      int row = linear >> 5, c16 = linear & 31;
      if (mt * 256 + row < cnt) {
        f16x8 v = *(const f16x8*)&tile[row * 256 + c16 * 8];
        *(f16x8*)(dbase + (size_t)row * D_IN + c16 * 8) = v;   // L3-allocate
      }
    }
  }
}

// ------- combine: out[t] = sum over s in {s0,s1}, kc in [0,4) of partial -------
__global__ __launch_bounds__(256) void combine_kernel(
    const f16* __restrict__ ypart, const int2* __restrict__ slotAB,
    float* __restrict__ out) {
  int i = blockIdx.x * 256 + threadIdx.x;
  int t = i >> 7;
  int c8 = i & 127;
  int2 s = slotAB[t];
  float sum[8] = {0.f, 0.f, 0.f, 0.f, 0.f, 0.f, 0.f, 0.f};
#pragma unroll
  for (int kc = 0; kc < KSPLIT; ++kc) {
    const f16* base = ypart + (size_t)kc * NSLOT_PAD * D_IN + c8 * 8;
    f16x8 y0 = *(const f16x8*)(base + (size_t)s.x * D_IN);
    f16x8 y1 = *(const f16x8*)(base + (size_t)s.y * D_IN);
#pragma unroll
    for (int j = 0; j < 8; ++j) sum[j] += (float)y0[j] + (float)y1[j];
  }
  float* o = out + (size_t)t * D_IN + c8 * 8;
  f32x4 o0 = {sum[0], sum[1], sum[2], sum[3]};
  f32x4 o1 = {sum[4], sum[5], sum[6], sum[7]};
  __builtin_nontemporal_store(o0, (f32x4*)o);
  __builtin_nontemporal_store(o1, (f32x4*)(o + 4));
}

// ---------------- launch ----------------

extern "C" void kernel_launch(void* const* d_in, const int* in_sizes, int n_in,
                              void* d_out, int out_size, void* d_ws, size_t ws_size,
                              hipStream_t stream) {
  const float* x  = (const float*)d_in[0];
  const float* Wr = (const float*)d_in[1];
  const float* br = (const float*)d_in[2];
  const float* Wg = (const float*)d_in[3];
  const float* bg = (const float*)d_in[4];
  const float* Wu = (const float*)d_in[5];
  const float* bu = (const float*)d_in[6];
  const float* Wd = (const float*)d_in[7];
  const float* bd = (const float*)d_in[8];
  float* out = (float*)d_out;

  char* ws = (char*)d_ws;
  size_t o = 0;
  auto alloc = [&](size_t bytes) {
    size_t r = o;
    o += (bytes + 255) & ~(size_t)255;
    return r;
  };
  f16* xb     = (f16*)(ws + alloc((size_t)T_TOK * D_IN * 2));               // 16MB
  f16* wgut   = (f16*)(ws + alloc((size_t)E_EXP * 2 * H_HID * D_IN * 2));   // 128MB
  f16* wdt    = (f16*)(ws + alloc((size_t)E_EXP * D_IN * H_HID * 2));       // 64MB
  f16* hbuf   = (f16*)(ws + alloc((size_t)NSLOT_PAD * H_HID * 2));          // 135MB
  int* eidx   = (int*)(ws + alloc((size_t)T_TOK * 4));
  float2* pval= (float2*)(ws + alloc((size_t)T_TOK * 8));
  int* counts = (int*)(ws + alloc(64 * 4));
  int* cursors = counts + 8;
  int* offsets = counts + 16;
  int* perm   = (int*)(ws + alloc((size_t)NSLOT_PAD * 4));
  float* gatew= (float*)(ws + alloc((size_t)NSLOT_PAD * 4));
  int2* slotAB= (int2*)(ws + alloc((size_t)T_TOK * 8));
  // ypart aliases xb+wgut (both dead after ffn1): 4*34MB = 136MB <= 144MB.
  f16* ypart  = xb;

  hipMemsetAsync(counts, 0, 64 * 4, stream);

  // prep: router (2048 blocks) + Wg/Wu/Wd transposes (3 x 8192 blocks)
  prep_kernel<<<dim3(T_TOK / 4 + 3 * 8192), 256, 0, stream>>>(
      x, Wr, br, Wg, Wu, Wd, eidx, pval, counts, xb, wgut, wdt);
  scan_kernel<<<1, 64, 0, stream>>>(counts, offsets);
  scatter_kernel<<<T_TOK / 256, 256, 0, stream>>>(eidx, pval, offsets, cursors,
                                                  perm, gatew, slotAB);
  // FFN1: 8192 blocks, XCD-panel affinity.
  ffn_8ph_kernel<0><<<dim3(8192), 512, 0, stream>>>(
      xb, wgut, bg, bu, offsets, perm, nullptr, hbuf);
  // FFN2: 4096 blocks, split-K=4, disjoint f16 partials (no atomics).
  ffn_8ph_kernel<1><<<dim3(4096), 512, 0, stream>>>(
      hbuf, wdt, bd, nullptr, offsets, nullptr, gatew, ypart);
  combine_kernel<<<T_TOK * D_IN / 8 / 256, 256, 0, stream>>>(ypart, slotAB, out);
}

// Round 17
// 926.450 us; speedup vs baseline: 1.2584x; 1.0060x over previous
//
#include <hip/hip_runtime.h>
#include <hip/hip_fp16.h>

// MoE: B=4 S=2048 D=1024 E=8 K=2 H=4096. T=8192 tokens, 16384 assignments.
// R17: kc-chunked layouts for FFN2's operands. Evidence: FFN2 has HALF the
// active blocks of FFN1 at identical per-block shape yet runs ~equal time
// -> per-block 2x. Only asymmetry: FFN2 panels have 8KB row stride (KD=4096,
// 2KB chunk consumed) -> L2 set-conflict evictions. Fix: wdt[e][kc][d][1024]
// and hbuf[kc][slot][1024] -> contiguous 512KB panels, 2KB rows (FFN1-shaped).
// R16's L3-allocating stores reverted (null): back to R14 nontemporal.

#define T_TOK 8192
#define D_IN  1024
#define E_EXP 8
#define H_HID 4096
#define NSLOT (T_TOK * 2)
#define NSLOT_PAD (NSLOT + 256)
#define KSPLIT 4

typedef _Float16 f16;
typedef __attribute__((ext_vector_type(8))) _Float16 f16x8;
typedef __attribute__((ext_vector_type(4))) _Float16 f16x4;
typedef __attribute__((ext_vector_type(4))) float f32x4;

__device__ __forceinline__ void gload_lds16(const void* g, void* l) {
  __builtin_amdgcn_global_load_lds(
      (const __attribute__((address_space(1))) unsigned int*)g,
      (__attribute__((address_space(3))) unsigned int*)l, 16, 0, 0);
}

// ---------------- prep: router (+x->f16) AND weight transposes, fused ----------------
// blocks [0,2048): router; then Wg (MAP1) / Wu (MAP2) -> wgut[e][2H][1024];
// Wd -> wdt[e][kc][d][1024] (kc-chunked).

__global__ __launch_bounds__(256) void prep_kernel(
    const float* __restrict__ x, const float* __restrict__ Wr,
    const float* __restrict__ br, const float* __restrict__ Wg,
    const float* __restrict__ Wu, const float* __restrict__ Wd,
    int* __restrict__ eidx, float2* __restrict__ pval,
    int* __restrict__ counts, f16* __restrict__ xb,
    f16* __restrict__ wgut, f16* __restrict__ wdt) {
  __shared__ float tile[128][33];
  int g = blockIdx.x;
  if (g < T_TOK / 4) {
    // ---- router ----
    int lane = threadIdx.x & 63, wid = threadIdx.x >> 6;
    int t = g * 4 + wid;
    const float* xr = x + (size_t)t * D_IN;
    float s[8] = {0.f, 0.f, 0.f, 0.f, 0.f, 0.f, 0.f, 0.f};
    int dbase = lane * 16;
#pragma unroll
    for (int i = 0; i < 4; ++i) {
      float4 xv = *(const float4*)(xr + dbase + i * 4);
      f16x4 xo = {(f16)xv.x, (f16)xv.y, (f16)xv.z, (f16)xv.w};
      *(f16x4*)(xb + (size_t)t * D_IN + dbase + i * 4) = xo;
      const float xs[4] = {xv.x, xv.y, xv.z, xv.w};
#pragma unroll
      for (int j = 0; j < 4; ++j) {
        const float* wr = Wr + (size_t)(dbase + i * 4 + j) * E_EXP;
        float4 w0 = *(const float4*)wr;
        float4 w1 = *(const float4*)(wr + 4);
        float xvj = xs[j];
        s[0] += xvj * w0.x; s[1] += xvj * w0.y; s[2] += xvj * w0.z; s[3] += xvj * w0.w;
        s[4] += xvj * w1.x; s[5] += xvj * w1.y; s[6] += xvj * w1.z; s[7] += xvj * w1.w;
      }
    }
#pragma unroll
    for (int off = 32; off; off >>= 1)
#pragma unroll
      for (int e = 0; e < 8; ++e) s[e] += __shfl_xor(s[e], off);
    if (lane == 0) {
      float v[8];
#pragma unroll
      for (int e = 0; e < 8; ++e) v[e] = s[e] + br[e];
      int i0 = 0; float v0 = v[0];
#pragma unroll
      for (int e = 1; e < 8; ++e) if (v[e] > v0) { v0 = v[e]; i0 = e; }
      int i1 = -1; float v1 = -1e30f;
#pragma unroll
      for (int e = 0; e < 8; ++e)
        if (e != i0 && v[e] > v1) { v1 = v[e]; i1 = e; }
      float ed = __expf(v1 - v0);
      float inv = 1.f / (1.f + ed);
      eidx[t] = i0 | (i1 << 8);
      pval[t] = make_float2(inv, ed * inv);
      atomicAdd(&counts[i0], 1);
      atomicAdd(&counts[i1], 1);
    }
    return;
  }
  // ---- transpose ----
  int i = g - T_TOK / 4;
  int which = i >> 13;          // 0=Wg, 1=Wu, 2=Wd
  int j = i & 8191;
  const float* src; int C, cx, cy, e;
  if (which < 2) {
    cx = j & 127; cy = (j >> 7) & 7; e = j >> 10;
    C = H_HID; src = (which == 0) ? Wg : Wu;
  } else {
    cx = j & 31; cy = (j >> 5) & 31; e = j >> 10;
    C = D_IN; src = Wd;
  }
  int R = (which < 2) ? D_IN : H_HID;
  const float* s = src + (size_t)e * R * C;
  int c0 = cx * 32, r0 = cy * 128;
#pragma unroll
  for (int q4 = 0; q4 < 4; ++q4) {
    int q = q4 * 256 + threadIdx.x;
    int r = q >> 3, c4 = (q & 7) * 4;
    float4 v = *(const float4*)(s + (size_t)(r0 + r) * C + c0 + c4);
    tile[r][c4 + 0] = v.x; tile[r][c4 + 1] = v.y;
    tile[r][c4 + 2] = v.z; tile[r][c4 + 3] = v.w;
  }
  __syncthreads();
#pragma unroll
  for (int w2 = 0; w2 < 2; ++w2) {
    int w = w2 * 256 + threadIdx.x;
    int col = w >> 4, oct = w & 15;
    int c = c0 + col;
    f16x8 o;
#pragma unroll
    for (int k = 0; k < 8; ++k) o[k] = (f16)tile[oct * 8 + k][col];
    if (which < 2) {
      // wgut[e][2H rows][1024]; gate/up 16-col interleave
      int ro = ((c >> 4) << 5) + ((which == 1) ? 16 : 0) + (c & 15);
      *(f16x8*)(wgut + ((size_t)e * 2 * H_HID + ro) * D_IN + r0 + oct * 8) = o;
    } else {
      // wdt[e][kc][d][1024]: kc = r0/1024, k' = r0%1024 + oct*8
      int kc = cy >> 3, k0 = (cy & 7) * 128;
      *(f16x8*)(wdt + (((size_t)e * 4 + kc) * 1024 + c) * 1024 + k0 + oct * 8) = o;
    }
  }
}

__global__ void scan_kernel(const int* __restrict__ counts, int* __restrict__ offsets) {
  if (threadIdx.x == 0) {
    int acc = 0;
#pragma unroll
    for (int e = 0; e < E_EXP; ++e) { offsets[e] = acc; acc += counts[e]; }
    offsets[E_EXP] = acc;
  }
}

__global__ __launch_bounds__(256) void scatter_kernel(
    const int* __restrict__ eidx, const float2* __restrict__ pval,
    const int* __restrict__ offsets, int* __restrict__ cursors,
    int* __restrict__ perm, float* __restrict__ gatew, int2* __restrict__ slotAB) {
  int t = blockIdx.x * 256 + threadIdx.x;
  if (t >= T_TOK) return;
  int ei = eidx[t];
  float2 p = pval[t];
  int e0 = ei & 0xff, e1 = (ei >> 8) & 0xff;
  int s0 = offsets[e0] + atomicAdd(&cursors[e0], 1);
  perm[s0] = t; gatew[s0] = p.x;
  int s1 = offsets[e1] + atomicAdd(&cursors[e1], 1);
  perm[s1] = t; gatew[s1] = p.y;
  slotAB[t] = make_int2(s0, s1);
}

// ---------------- 8-phase 256x256 grouped GEMM ----------------
// R8 schedule; R12 repack epilogue; R14 bare-s_barrier + nontemporal.
// R17: all A/B rows are 1024-long contiguous panels in BOTH modes.
// MODE0 (FFN1): A=xb via perm, B=wgut; out -> hbuf[kc][slot][1024].
// MODE1 (FFN2): A=hbuf[kc], B=wdt[e][kc]; out -> ypart[kc][slot][D].

#define BAR __builtin_amdgcn_s_barrier()
#define VMCNT(N) asm volatile("s_waitcnt vmcnt(" #N ")" ::: "memory")

#define STAGE_(B, ISB, H, KT, BASE) do {                                   \
  char* d_ = smem + (B)*65536 + (ISB)*32768 + (H)*16384 + wid*1024;        \
  gload_lds16(BASE[(H)*2+0] + (size_t)(KT)*64, d_);                        \
  gload_lds16(BASE[(H)*2+1] + (size_t)(KT)*64, d_ + 8192);                 \
} while (0)

#define LDA_(B, Q)                                                          \
  _Pragma("unroll")                                                         \
  for (int m_ = 0; m_ < 4; ++m_) {                                          \
    fa[m_][0] = *(const f16x8*)(smem + (B)*65536 + aoff + ((Q)*4+m_)*2048 + offk0); \
    fa[m_][1] = *(const f16x8*)(smem + (B)*65536 + aoff + ((Q)*4+m_)*2048 + offk1); \
  }

#define LDB_(FB, B, RH)                                                     \
  _Pragma("unroll")                                                         \
  for (int n_ = 0; n_ < 2; ++n_) {                                          \
    FB[n_][0] = *(const f16x8*)(smem + (B)*65536 + 32768 + boff + ((RH)*2+n_)*2048 + offk0); \
    FB[n_][1] = *(const f16x8*)(smem + (B)*65536 + 32768 + boff + ((RH)*2+n_)*2048 + offk1); \
  }

#define QUAD_(Q, RH, FB)                                                    \
  __builtin_amdgcn_s_setprio(1);                                            \
  _Pragma("unroll")                                                         \
  for (int m_ = 0; m_ < 4; ++m_)                                            \
    _Pragma("unroll")                                                       \
    for (int n_ = 0; n_ < 2; ++n_) {                                        \
      acc[(Q)*4+m_][(RH)*2+n_] = __builtin_amdgcn_mfma_f32_16x16x32_f16(    \
          fa[m_][0], FB[n_][0], acc[(Q)*4+m_][(RH)*2+n_], 0, 0, 0);         \
      acc[(Q)*4+m_][(RH)*2+n_] = __builtin_amdgcn_mfma_f32_16x16x32_f16(    \
          fa[m_][1], FB[n_][1], acc[(Q)*4+m_][(RH)*2+n_], 0, 0, 0);         \
    }                                                                       \
  __builtin_amdgcn_s_setprio(0);

template<int MODE>
__global__ __launch_bounds__(512, 2) void ffn_8ph_kernel(
    const f16* __restrict__ Asrc, const f16* __restrict__ Bsrc,
    const float* __restrict__ bias0, const float* __restrict__ bias1,
    const int* __restrict__ offsets, const int* __restrict__ perm,
    const float* __restrict__ gatew, f16* __restrict__ dst) {
  constexpr int NT = 16;

  __shared__ __align__(16) char smem[131072];

  int g = blockIdx.x;
  int xcd = g & 7;
  int mt = (g >> 3) & 31;
  int e, nt, kc;
  if constexpr (MODE == 0) {
    int panel = xcd + 8 * (g >> 8);   // [0,256)
    e = panel >> 5; nt = panel & 31; kc = 0;
  } else {
    int sp = xcd + 8 * (g >> 8);      // [0,128)
    e = sp >> 4; nt = (sp >> 2) & 3; kc = sp & 3;
  }

  int off = offsets[e];
  int cnt = offsets[e + 1] - off;
  if (mt * 256 >= cnt) return;

  int tid = threadIdx.x, lane = tid & 63, wid = tid >> 6;
  int wm = wid >> 2, wn = wid & 3;
  int l15 = lane & 15, lc0 = lane >> 4, s7 = l15 & 7;
  int aoff = (wm * 128 + l15) * 128;
  int boff = (wn * 64 + l15) * 128;
  int offk0 = ((lc0) ^ s7) * 16;
  int offk1 = ((lc0 + 4) ^ s7) * 16;

  int rowh_[2], lc_[2];
#pragma unroll
  for (int i = 0; i < 2; ++i) {
    int chunk = (i * 8 + wid) * 64 + lane;
    rowh_[i] = chunk >> 3;
    lc_[i] = (chunk & 7) ^ (rowh_[i] & 7);
  }

  const f16 *aB[4], *bB[4];
#pragma unroll
  for (int h = 0; h < 2; ++h)
#pragma unroll
    for (int i = 0; i < 2; ++i) {
      int absrow = h * 128 + rowh_[i];
      int slot = off + min(mt * 256 + absrow, cnt - 1);
      if constexpr (MODE == 0) {
        bB[h * 2 + i] = Bsrc + ((size_t)e * 2 * H_HID + nt * 256 + absrow) * 1024 +
                        lc_[i] * 8;
        aB[h * 2 + i] = Asrc + (size_t)perm[slot] * 1024 + lc_[i] * 8;
      } else {
        bB[h * 2 + i] = Bsrc + (((size_t)e * 4 + kc) * 1024 + nt * 256 + absrow) * 1024 +
                        lc_[i] * 8;
        aB[h * 2 + i] = Asrc + ((size_t)kc * NSLOT_PAD + slot) * 1024 + lc_[i] * 8;
      }
    }

  float bv0[4], bv1[2];
  if constexpr (MODE == 0) {
#pragma unroll
    for (int p = 0; p < 2; ++p) {
      int h = nt * 128 + wn * 32 + p * 16 + l15;
      bv0[p] = bias0[e * H_HID + h];
      bv1[p] = bias1[e * H_HID + h];
    }
  } else {
#pragma unroll
    for (int n = 0; n < 4; ++n)
      bv0[n] = (kc == 0)
                   ? bias0[e * D_IN + nt * 256 + wn * 64 + n * 16 + l15]
                   : 0.f;
  }

  f32x4 acc[8][4] = {};
  f16x8 fa[4][2], fb01[2][2], fb23[2][2];

  // prologue: buf0.B, buf0.A (t0); buf1.B (t1); buf1.A-H0 (t1) — 14 loads.
  STAGE_(0, 1, 0, 0, bB); STAGE_(0, 1, 1, 0, bB);
  STAGE_(0, 0, 0, 0, aB); STAGE_(0, 0, 1, 0, aB);
  STAGE_(1, 1, 0, 1, bB); STAGE_(1, 1, 1, 1, bB);
  STAGE_(1, 0, 0, 1, aB);
  VMCNT(6);
  BAR;

  for (int it = 0; it < NT / 2; ++it) {
    int b_ = 2 * it + 1;
    int a2 = min(2 * it + 2, NT - 1);
    int b2 = min(2 * it + 3, NT - 1);
    // P1
    LDA_(0, 0); LDB_(fb01, 0, 0); STAGE_(1, 0, 1, b_, aB);
    BAR; QUAD_(0, 0, fb01); BAR;
    // P2
    LDB_(fb23, 0, 1);
    BAR; QUAD_(0, 1, fb23); BAR;
    // P3
    LDA_(0, 1); STAGE_(0, 1, 0, a2, bB);
    BAR; QUAD_(1, 0, fb01); BAR;
    // P4
    STAGE_(0, 1, 1, a2, bB);
    BAR; QUAD_(1, 1, fb23);
    VMCNT(4);
    BAR;
    // P5
    LDA_(1, 0); LDB_(fb01, 1, 0); STAGE_(0, 0, 0, a2, aB);
    BAR; QUAD_(0, 0, fb01); BAR;
    // P6
    LDB_(fb23, 1, 1); STAGE_(0, 0, 1, a2, aB);
    BAR; QUAD_(0, 1, fb23); BAR;
    // P7
    LDA_(1, 1); STAGE_(1, 1, 0, b2, bB);
    BAR; QUAD_(1, 0, fb01); BAR;
    // P8
    STAGE_(1, 1, 1, b2, bB); STAGE_(1, 0, 0, b2, aB);
    BAR; QUAD_(1, 1, fb23);
    VMCNT(6);
    BAR;
  }

  // drain ALL staging loads before reusing LDS for the repack tile
  VMCNT(0);
  __syncthreads();

  int c0_ = lc0 * 4;
  f16* tile = (f16*)smem;
  if constexpr (MODE == 0) {
    // repack: [256][128] f16 (64KB)
#pragma unroll
    for (int p = 0; p < 2; ++p) {
      int colL = wn * 32 + p * 16 + l15;
#pragma unroll
      for (int m = 0; m < 8; ++m) {
        int row = wm * 128 + m * 16 + c0_;
#pragma unroll
        for (int r = 0; r < 4; ++r) {
          float gv = acc[m][2 * p][r] + bv0[p];
          float uv = acc[m][2 * p + 1][r] + bv1[p];
          tile[(row + r) * 128 + colL] = (f16)((gv / (1.f + __expf(-gv))) * uv);
        }
      }
    }
    __syncthreads();
    // hbuf[kcH][slot][1024]: kcH = nt>>3, inner h-offset (nt&7)*128
    f16* dbase = dst + ((size_t)(nt >> 3) * NSLOT_PAD + off + mt * 256) * 1024 +
                 (nt & 7) * 128;
#pragma unroll
    for (int i = 0; i < 8; ++i) {
      int linear = i * 512 + tid;
      int row = linear >> 4, c16 = linear & 15;
      if (mt * 256 + row < cnt) {
        f16x8 v = *(const f16x8*)&tile[row * 128 + c16 * 8];
        __builtin_nontemporal_store(v, (f16x8*)(dbase + (size_t)row * 1024 + c16 * 8));
      }
    }
  } else {
    // repack: [256][256] f16 (128KB)
#pragma unroll
    for (int n = 0; n < 4; ++n) {
      int colL = wn * 64 + n * 16 + l15;
#pragma unroll
      for (int m = 0; m < 8; ++m) {
        int row = wm * 128 + m * 16 + c0_;
#pragma unroll
        for (int r = 0; r < 4; ++r) {
          int slot = off + min(mt * 256 + row + r, cnt - 1);
          tile[(row + r) * 256 + colL] =
              (f16)(gatew[slot] * (acc[m][n][r] + bv0[n]));
        }
      }
    }
    __syncthreads();
    f16* dstP = dst + (size_t)kc * NSLOT_PAD * D_IN;
    f16* dbase = dstP + (size_t)(off + mt * 256) * D_IN + nt * 256;
#pragma unroll
    for (int i = 0; i < 16; ++i) {
      int linear = i * 512 + tid;
      int row = linear >> 5, c16 = linear & 31;
      if (mt * 256 + row < cnt) {
        f16x8 v = *(const f16x8*)&tile[row * 256 + c16 * 8];
        __builtin_nontemporal_store(v, (f16x8*)(dbase + (size_t)row * D_IN + c16 * 8));
      }
    }
  }
}

// ------- combine: out[t] = sum over s in {s0,s1}, kc in [0,4) of partial -------
__global__ __launch_bounds__(256) void combine_kernel(
    const f16* __restrict__ ypart, const int2* __restrict__ slotAB,
    float* __restrict__ out) {
  int i = blockIdx.x * 256 + threadIdx.x;
  int t = i >> 7;
  int c8 = i & 127;
  int2 s = slotAB[t];
  float sum[8] = {0.f, 0.f, 0.f, 0.f, 0.f, 0.f, 0.f, 0.f};
#pragma unroll
  for (int kc = 0; kc < KSPLIT; ++kc) {
    const f16* base = ypart + (size_t)kc * NSLOT_PAD * D_IN + c8 * 8;
    f16x8 y0 = *(const f16x8*)(base + (size_t)s.x * D_IN);
    f16x8 y1 = *(const f16x8*)(base + (size_t)s.y * D_IN);
#pragma unroll
    for (int j = 0; j < 8; ++j) sum[j] += (float)y0[j] + (float)y1[j];
  }
  float* o = out + (size_t)t * D_IN + c8 * 8;
  f32x4 o0 = {sum[0], sum[1], sum[2], sum[3]};
  f32x4 o1 = {sum[4], sum[5], sum[6], sum[7]};
  __builtin_nontemporal_store(o0, (f32x4*)o);
  __builtin_nontemporal_store(o1, (f32x4*)(o + 4));
}

// ---------------- launch ----------------

extern "C" void kernel_launch(void* const* d_in, const int* in_sizes, int n_in,
                              void* d_out, int out_size, void* d_ws, size_t ws_size,
                              hipStream_t stream) {
  const float* x  = (const float*)d_in[0];
  const float* Wr = (const float*)d_in[1];
  const float* br = (const float*)d_in[2];
  const float* Wg = (const float*)d_in[3];
  const float* bg = (const float*)d_in[4];
  const float* Wu = (const float*)d_in[5];
  const float* bu = (const float*)d_in[6];
  const float* Wd = (const float*)d_in[7];
  const float* bd = (const float*)d_in[8];
  float* out = (float*)d_out;

  char* ws = (char*)d_ws;
  size_t o = 0;
  auto alloc = [&](size_t bytes) {
    size_t r = o;
    o += (bytes + 255) & ~(size_t)255;
    return r;
  };
  f16* xb     = (f16*)(ws + alloc((size_t)T_TOK * D_IN * 2));               // 16MB
  f16* wgut   = (f16*)(ws + alloc((size_t)E_EXP * 2 * H_HID * D_IN * 2));   // 128MB
  f16* wdt    = (f16*)(ws + alloc((size_t)E_EXP * D_IN * H_HID * 2));       // 64MB
  f16* hbuf   = (f16*)(ws + alloc((size_t)KSPLIT * NSLOT_PAD * 1024 * 2));  // 135MB
  int* eidx   = (int*)(ws + alloc((size_t)T_TOK * 4));
  float2* pval= (float2*)(ws + alloc((size_t)T_TOK * 8));
  int* counts = (int*)(ws + alloc(64 * 4));
  int* cursors = counts + 8;
  int* offsets = counts + 16;
  int* perm   = (int*)(ws + alloc((size_t)NSLOT_PAD * 4));
  float* gatew= (float*)(ws + alloc((size_t)NSLOT_PAD * 4));
  int2* slotAB= (int2*)(ws + alloc((size_t)T_TOK * 8));
  // ypart aliases xb+wgut (both dead after ffn1): 4*34MB = 136MB <= 144MB.
  f16* ypart  = xb;

  hipMemsetAsync(counts, 0, 64 * 4, stream);

  // prep: router (2048 blocks) + Wg/Wu/Wd transposes (3 x 8192 blocks)
  prep_kernel<<<dim3(T_TOK / 4 + 3 * 8192), 256, 0, stream>>>(
      x, Wr, br, Wg, Wu, Wd, eidx, pval, counts, xb, wgut, wdt);
  scan_kernel<<<1, 64, 0, stream>>>(counts, offsets);
  scatter_kernel<<<T_TOK / 256, 256, 0, stream>>>(eidx, pval, offsets, cursors,
                                                  perm, gatew, slotAB);
  // FFN1: 8192 blocks, XCD-panel affinity.
  ffn_8ph_kernel<0><<<dim3(8192), 512, 0, stream>>>(
      xb, wgut, bg, bu, offsets, perm, nullptr, hbuf);
  // FFN2: 4096 blocks, split-K=4, disjoint f16 partials.
  ffn_8ph_kernel<1><<<dim3(4096), 512, 0, stream>>>(
      hbuf, wdt, bd, nullptr, offsets, nullptr, gatew, ypart);
  combine_kernel<<<T_TOK * D_IN / 8 / 256, 256, 0, stream>>>(ypart, slotAB, out);
}